// Round 3
// baseline (196.525 us; speedup 1.0000x reference)
//
#include <hip/hip_runtime.h>
#include <hip/hip_bf16.h>

// GAT on two 512-node cliques + bipartite cross edges, 5 GATConv layers.
//
// R16: replace the bucket-sort softmax (7 barriers, shuffle scans, LDS
// atomics, 1 block/CU, measured ~31us/layer with VALUBusy ~8% -> pure
// dependent-chain stall) with the DENSE formulation: per dst, loop all 512
// srcs with a compare-gated 4-FMA accumulate.  Same factored math as the
// verified version: den = F1*Sum[s>=th]e1 + F2*Sum[s<th]e2 (and h-weighted
// twins); branch chosen via e1_i >= exp(-d_j) (exp monotone).  One barrier,
// zero cross-lane ops, 131072 independent dst-head items -> issue-bound.
// Also: prep reads made perfectly coalesced (c = idx&127 so addr == idx);
// W1 transpose reads coalesced / writes strided.
// gemm/mm2/att2 kernels unchanged from R15 (verified bit-exact).

typedef __hip_bfloat16 bf16;

__device__ __forceinline__ float b2f(bf16 x) { return __bfloat162float(x); }

__device__ __forceinline__ int detect_bf16(const void* desc1) {
  const unsigned* u = (const unsigned*)desc1;
  int hits = 0;
#pragma unroll 8
  for (int i = 0; i < 256; ++i) {
    unsigned e = (u[i] >> 7) & 0xFFu;
    hits += (e >= 100u && e <= 140u) ? 1 : 0;
  }
  return hits >= 200 ? 1 : 0;
}

__device__ __forceinline__ float load_in(const void* p, int i, int bf) {
  return bf ? b2f(((const bf16*)p)[i]) : ((const float*)p)[i];
}

// ---------------------------------------------------------------- prep ----
// xt packed: xt[((c>>2)*1024 + n)*4 + (c&3)].
// W1t transposed: W1t[hd*128 + k] = W1[k*128 + hd]; coalesced reads,
// strided (fire-and-forget) writes.
__global__ __launch_bounds__(256) void prep_kernel(
    const void* __restrict__ desc1, const void* __restrict__ desc2,
    const void* __restrict__ W1,   const void* __restrict__ as1,
    const void* __restrict__ ad1,  const void* __restrict__ b1,
    const void* __restrict__ W2,   const void* __restrict__ as2,
    const void* __restrict__ ad2,  const void* __restrict__ b2,
    float* __restrict__ xt, float* __restrict__ W1t, float* __restrict__ W2f,
    float* __restrict__ vecs, int* __restrict__ flag) {
  const int bf = detect_bf16(desc1);
  if (blockIdx.x == 0 && threadIdx.x == 0) *flag = bf;
  const int total = 131072 + 16384 + 16384 + 6 * 128;
  for (int idx = blockIdx.x * blockDim.x + threadIdx.x; idx < total;
       idx += gridDim.x * blockDim.x) {
    if (idx < 131072) {
      // n = idx>>7, c = idx&127  ->  n*128 + c == idx: reads are linear.
      int c = idx & 127, n = idx >> 7;
      float v = (n < 512) ? load_in(desc1, idx, bf)
                          : load_in(desc2, idx - 65536, bf);
      xt[((c >> 2) * 1024 + n) * 4 + (c & 3)] = v;
    } else if (idx < 147456) {
      int i = idx - 131072;            // i = k*128 + hd (W1 row-major)
      int k = i >> 7, hdd = i & 127;
      W1t[hdd * 128 + k] = load_in(W1, i, bf);
    } else if (idx < 163840) {
      W2f[idx - 147456] = load_in(W2, idx - 147456, bf);
    } else {
      int i = idx - 163840, o = i & 127;
      float v;
      if      (i < 128) v = load_in(as1, o, bf);
      else if (i < 256) v = load_in(ad1, o, bf);
      else if (i < 384) v = load_in(b1, o, bf);
      else if (i < 512) v = load_in(as2, o, bf);
      else if (i < 640) v = load_in(ad2, o, bf);
      else              v = load_in(b2, o, bf);
      vecs[i] = v;
    }
  }
}

// ------------------------------------------------------------ layer GEMM ----
// Ht[hd*1024 + node] = dot(x[node,:], W1[:,hd]).  512 blocks x 256 threads:
// block = (chunk of 256 nodes, head).  W column broadcast from LDS; x reads
// coalesced float4; write coalesced.  FMA order identical to R13 phase A.
__global__ __launch_bounds__(256, 2) void gemm_kernel(
    const float* __restrict__ xt_in, const float* __restrict__ W1t,
    float* __restrict__ Ht) {
  __shared__ float wcol[128];
  const int tid = threadIdx.x;
  const int hd = blockIdx.x & 127;
  const int chunk = blockIdx.x >> 7;
  const int node = chunk * 256 + tid;
  if (tid < 32) ((float4*)wcol)[tid] = ((const float4*)(W1t + hd * 128))[tid];
  __syncthreads();
  const float4* x4 = (const float4*)xt_in;
  float acc0 = 0.f, acc1 = 0.f;
  for (int cc = 0; cc < 32; cc += 8) {
    float4 xs[8];
#pragma unroll
    for (int u = 0; u < 8; ++u) xs[u] = x4[(cc + u) * 1024 + node];
#pragma unroll
    for (int u = 0; u < 8; ++u) {
      const int k = (cc + u) * 4;
      acc0 = fmaf(xs[u].x, wcol[k],     acc0);
      acc1 = fmaf(xs[u].y, wcol[k + 1], acc1);
      acc0 = fmaf(xs[u].z, wcol[k + 2], acc0);
      acc1 = fmaf(xs[u].w, wcol[k + 3], acc1);
    }
  }
  Ht[hd * 1024 + node] = acc0 + acc1;
}

// ------------------------------------------------------------ layer attn ----
// DENSE softmax-aggregate.  grid 512 = (half<<8)|(S<<7)|hd, 256 threads.
// Block stages all 512 srcs of set S for head hd into LDS (e1, e2, e1*h,
// e2*h); each thread owns one dst j = half*256+tid of set D and loops all
// srcs: m = (e1_i >= exp(-d_j)) selects the leaky-relu branch (exp is
// monotone, so this is s_i >= -d_j).  den = F1*M1 + F2*N2, num likewise --
// identical factored form to the verified bucket version; only the
// summation order differs (src-index order).
template <int CROSS>
__global__ __launch_bounds__(256, 2) void attn_kernel(
    const float* __restrict__ Ht, float* __restrict__ xt_out,
    const float* __restrict__ vecs) {
  __shared__ __align__(16) float4 sE[512];  // (e1, e2, e1*h, e2*h)
  const int tid  = threadIdx.x;
  const int hd   = blockIdx.x & 127;
  const int S    = (blockIdx.x >> 7) & 1;
  const int half = blockIdx.x >> 8;
  const int D    = CROSS ? (1 - S) : S;
  const float a_src = vecs[hd], a_dst = vecs[128 + hd], bias = vecs[256 + hd];
  const float* HtH = Ht + hd * 1024;

  // stage 2 srcs per thread (coalesced Ht reads)
#pragma unroll
  for (int u = 0; u < 2; ++u) {
    const int i = u * 256 + tid;
    const float h = HtH[S * 512 + i];
    const float s = h * a_src;
    const float e1 = __expf(s), e2 = __expf(0.2f * s);
    sE[i] = make_float4(e1, e2, e1 * h, e2 * h);
  }
  // dst-side precompute
  const int j = half * 256 + tid;
  const float hD    = HtH[D * 512 + j];
  const float d_own = hD * a_dst;
  const float F1  = __expf(d_own), F2 = __expf(0.2f * d_own);
  const float eTh = __expf(-d_own);  // exp(theta), theta = -d_own
  __syncthreads();

  float M1 = 0.f, M1h = 0.f, N2 = 0.f, N2h = 0.f;
#pragma unroll 8
  for (int i = 0; i < 512; ++i) {
    const float4 r = sE[i];            // broadcast ds_read_b128
    const float m = (r.x >= eTh) ? 1.0f : 0.0f;
    const float n = (r.x >= eTh) ? 0.0f : 1.0f;
    M1  = fmaf(m, r.x, M1);
    M1h = fmaf(m, r.z, M1h);
    N2  = fmaf(n, r.y, N2);
    N2h = fmaf(n, r.w, N2h);
  }
  float den = fmaf(F1, M1,  F2 * N2);
  float num = fmaf(F1, M1h, F2 * N2h);
  if (CROSS) {  // self-loop: dst node's own source score
    const float t = hD * a_src + d_own;
    const float p = __expf(fmaxf(t, 0.2f * t));
    den += p;
    num = fmaf(p, hD, num);
  }
  float o = num / (den + 1e-16f) + bias;
  o = (o > 0.f) ? o : expm1f(o);  // ELU
  // packed layout: xt_out[((hd>>2)*1024 + node)*4 + (hd&3)]
  xt_out[(((hd >> 2) * 1024) + D * 512 + j) * 4 + (hd & 3)] = o;
}

// ----------------------------------------------------- final layer: mm2 ----
// grid 512 x 256: 2 rows x 128 cols per block.  h2 = x@W2, s2/d2 row dots.
__global__ __launch_bounds__(256, 2) void mm2_kernel(
    const float* __restrict__ xt_in, const float* __restrict__ W2f,
    const float* __restrict__ vecs, float* __restrict__ h2,
    float* __restrict__ s2, float* __restrict__ d2) {
  __shared__ float rs[256], rd[256];
  const int tid = threadIdx.x;
  const int row = blockIdx.x * 2 + (tid >> 7);
  const int c = tid & 127;
  float acc0 = 0.f, acc1 = 0.f;
  {
    const float4* x4 = (const float4*)xt_in;
    for (int cc = 0; cc < 32; cc += 8) {
      float4 xb[8];
#pragma unroll
      for (int u = 0; u < 8; ++u) xb[u] = x4[(cc + u) * 1024 + row];
#pragma unroll
      for (int u = 0; u < 8; ++u) {
        const int k = (cc + u) * 4;
        acc0 = fmaf(xb[u].x, W2f[k * 128 + c],       acc0);
        acc1 = fmaf(xb[u].y, W2f[(k + 1) * 128 + c], acc1);
        acc0 = fmaf(xb[u].z, W2f[(k + 2) * 128 + c], acc0);
        acc1 = fmaf(xb[u].w, W2f[(k + 3) * 128 + c], acc1);
      }
    }
  }
  float acc = acc0 + acc1;
  h2[row * 128 + c] = acc;
  rs[tid] = acc * vecs[384 + c];  // a_src2
  rd[tid] = acc * vecs[512 + c];  // a_dst2
  __syncthreads();
  for (int off = 64; off > 0; off >>= 1) {
    if ((tid & 127) < off) { rs[tid] += rs[tid + off]; rd[tid] += rd[tid + off]; }
    __syncthreads();
  }
  if ((tid & 127) == 0) {
    s2[row] = rs[tid];
    d2[row] = rd[tid];
  }
}

// ---------------------------------------------------- final layer: attn ----
// Final conv: heads=1, ch=128, cross edges + self, no ELU, +b2.
// 512 blocks x 256 threads: 2 dsts/block.
__global__ __launch_bounds__(256, 2) void att2_kernel(
    const float* __restrict__ h2, const float* __restrict__ s2,
    const float* __restrict__ d2, const float* __restrict__ vecs,
    void* __restrict__ out, const int* __restrict__ flag) {
  __shared__ __align__(16) float pT[512 * 2];  // pT[j*2 + ld]
  const int tid = threadIdx.x;
  const int dstBase = blockIdx.x * 2;
  const int srcBase = (dstBase < 512) ? 512 : 0;  // cross edges

  for (int e = tid; e < 1024; e += 256) {
    int j = e >> 1, ld = e & 1;
    float t = s2[srcBase + j] + d2[dstBase + ld];
    pT[e] = __expf(fmaxf(t, 0.2f * t));
  }
  __syncthreads();

  const int c = tid & 127;
  const int g = tid >> 7;            // 0 or 1 -> dst within block
  const int i0 = dstBase + g;
  float den = 0.f, num = 0.f;
  const float* hrow = h2 + srcBase * 128 + c;
  for (int j0 = 0; j0 < 512; j0 += 8) {
    float hb[8];
#pragma unroll
    for (int u = 0; u < 8; ++u) hb[u] = hrow[(j0 + u) * 128];
#pragma unroll
    for (int u = 0; u < 8; ++u) {
      float p = pT[(j0 + u) * 2 + g];
      den += p;
      num = fmaf(p, hb[u], num);
    }
  }
  // self-loop
  float ts = s2[i0] + d2[i0];
  float ps = __expf(fmaxf(ts, 0.2f * ts));
  den += ps;
  num = fmaf(ps, h2[i0 * 128 + c], num);

  float o = num / (den + 1e-16f) + vecs[640 + c];
  if (*flag) ((bf16*)out)[i0 * 128 + c] = __float2bfloat16(o);
  else       ((float*)out)[i0 * 128 + c] = o;
}

// ------------------------------------------------------------- launcher ----
extern "C" void kernel_launch(void* const* d_in, const int* in_sizes, int n_in,
                              void* d_out, int out_size, void* d_ws, size_t ws_size,
                              hipStream_t stream) {
  (void)in_sizes; (void)n_in; (void)out_size; (void)ws_size;
  float* ws   = (float*)d_ws;
  float* xtA  = ws;            // 131072 (packed float4 layout)
  float* xtB  = ws + 131072;   // 131072 (packed float4 layout)
  float* h2   = ws + 262144;   // 131072 (row-major); ALSO aliased as Ht
  float* Ht   = h2;            // Ht[hd*1024+node]; dead once mm2 runs
  float* W1t  = ws + 393216;   // 16384 (transposed W1)
  float* W2f  = ws + 409600;   // 16384
  float* vecs = ws + 425984;   // 768
  float* s2   = ws + 426752;   // 1024
  float* d2   = ws + 427776;   // 1024
  int*   flag = (int*)(ws + 428800);

  prep_kernel<<<256, 256, 0, stream>>>(d_in[0], d_in[1], d_in[2], d_in[3],
                                       d_in[4], d_in[5], d_in[6], d_in[7],
                                       d_in[8], d_in[9], xtA, W1t, W2f, vecs,
                                       flag);
  // L1 inside
  gemm_kernel<<<512, 256, 0, stream>>>(xtA, W1t, Ht);
  attn_kernel<0><<<512, 256, 0, stream>>>(Ht, xtB, vecs);
  // L2 cross
  gemm_kernel<<<512, 256, 0, stream>>>(xtB, W1t, Ht);
  attn_kernel<1><<<512, 256, 0, stream>>>(Ht, xtA, vecs);
  // L3 inside
  gemm_kernel<<<512, 256, 0, stream>>>(xtA, W1t, Ht);
  attn_kernel<0><<<512, 256, 0, stream>>>(Ht, xtB, vecs);
  // L4 cross
  gemm_kernel<<<512, 256, 0, stream>>>(xtB, W1t, Ht);
  attn_kernel<1><<<512, 256, 0, stream>>>(Ht, xtA, vecs);
  // final layer
  mm2_kernel<<<512, 256, 0, stream>>>(xtA, W2f, vecs, h2, s2, d2);
  att2_kernel<<<512, 256, 0, stream>>>(h2, s2, d2, vecs, d_out, flag);
}

// Round 4
// 195.642 us; speedup vs baseline: 1.0045x; 1.0045x over previous
//
#include <hip/hip_runtime.h>
#include <hip/hip_bf16.h>

// GAT on two 512-node cliques + bipartite cross edges, 5 GATConv layers.
//
// R17: occupancy fix for the dense attention.  Evidence across R13/R15/R16:
// any "1 dst per thread, <=2 blocks/CU" attn kernel costs ~37-43us with
// VALUBusy ~7% and Occupancy ~5% (only ~3-7us of real VALU work) -- pure
// latency stall at 2 waves/SIMD.  att2 (same 512-iter loop shape, deeper
// load pipelining) runs ~3us.  Fix: 8 LANES per (dst,head) item ->
// 4096 blocks x 256 thr, 8 blocks/CU resident (launch_bounds(256,8),
// VGPR<=64), 32 waves/CU.  Inner loop: stride-8 LDS float4 walk (8 lanes x
// 16B = 128B = all 32 banks once, broadcast across 8-groups; conflict-free),
// 64 gated FMAs, then 3-step shfl_xor reduce.  Per-thread instrs drop 8x.
// Also: activations now PLANAR [ch][node] so attn writes are perfectly
// coalesced (packed-float4 layout forced a 4B-stride-16B scatter);
// gemm/mm2 read planar (coalesced / broadcast).  Math identical to R16's
// verified factored form (only fp32 summation order differs).

typedef __hip_bfloat16 bf16;

__device__ __forceinline__ float b2f(bf16 x) { return __bfloat162float(x); }

__device__ __forceinline__ int detect_bf16(const void* desc1) {
  const unsigned* u = (const unsigned*)desc1;
  int hits = 0;
#pragma unroll 8
  for (int i = 0; i < 256; ++i) {
    unsigned e = (u[i] >> 7) & 0xFFu;
    hits += (e >= 100u && e <= 140u) ? 1 : 0;
  }
  return hits >= 200 ? 1 : 0;
}

__device__ __forceinline__ float load_in(const void* p, int i, int bf) {
  return bf ? b2f(((const bf16*)p)[i]) : ((const float*)p)[i];
}

// ---------------------------------------------------------------- prep ----
// xt PLANAR: xt[c*1024 + n].  Reads perfectly linear; writes strided (tiny).
// W1t transposed: W1t[hd*128 + k] = W1[k*128 + hd].
__global__ __launch_bounds__(256) void prep_kernel(
    const void* __restrict__ desc1, const void* __restrict__ desc2,
    const void* __restrict__ W1,   const void* __restrict__ as1,
    const void* __restrict__ ad1,  const void* __restrict__ b1,
    const void* __restrict__ W2,   const void* __restrict__ as2,
    const void* __restrict__ ad2,  const void* __restrict__ b2,
    float* __restrict__ xt, float* __restrict__ W1t, float* __restrict__ W2f,
    float* __restrict__ vecs, int* __restrict__ flag) {
  const int bf = detect_bf16(desc1);
  if (blockIdx.x == 0 && threadIdx.x == 0) *flag = bf;
  const int total = 131072 + 16384 + 16384 + 6 * 128;
  for (int idx = blockIdx.x * blockDim.x + threadIdx.x; idx < total;
       idx += gridDim.x * blockDim.x) {
    if (idx < 131072) {
      int c = idx & 127, n = idx >> 7;    // reads are linear in idx
      float v = (n < 512) ? load_in(desc1, idx, bf)
                          : load_in(desc2, idx - 65536, bf);
      xt[c * 1024 + n] = v;
    } else if (idx < 147456) {
      int i = idx - 131072;               // i = k*128 + hd (W1 row-major)
      int k = i >> 7, hdd = i & 127;
      W1t[hdd * 128 + k] = load_in(W1, i, bf);
    } else if (idx < 163840) {
      W2f[idx - 147456] = load_in(W2, idx - 147456, bf);
    } else {
      int i = idx - 163840, o = i & 127;
      float v;
      if      (i < 128) v = load_in(as1, o, bf);
      else if (i < 256) v = load_in(ad1, o, bf);
      else if (i < 384) v = load_in(b1, o, bf);
      else if (i < 512) v = load_in(as2, o, bf);
      else if (i < 640) v = load_in(ad2, o, bf);
      else              v = load_in(b2, o, bf);
      vecs[i] = v;
    }
  }
}

// ------------------------------------------------------------ layer GEMM ----
// Ht[hd*1024 + node] = dot(x[node,:], W1[:,hd]).  512 blocks x 256 threads.
// Planar x reads: xt[k*1024 + node] coalesced dword per k; W col from LDS.
// Even-k -> acc0, odd-k -> acc1 (same alternation as verified kernels).
__global__ __launch_bounds__(256, 2) void gemm_kernel(
    const float* __restrict__ xt_in, const float* __restrict__ W1t,
    float* __restrict__ Ht) {
  __shared__ float wcol[128];
  const int tid = threadIdx.x;
  const int hd = blockIdx.x & 127;
  const int chunk = blockIdx.x >> 7;
  const int node = chunk * 256 + tid;
  if (tid < 32) ((float4*)wcol)[tid] = ((const float4*)(W1t + hd * 128))[tid];
  __syncthreads();
  float acc0 = 0.f, acc1 = 0.f;
  for (int k0 = 0; k0 < 128; k0 += 8) {
    float xb[8];
#pragma unroll
    for (int u = 0; u < 8; ++u) xb[u] = xt_in[(k0 + u) * 1024 + node];
#pragma unroll
    for (int u = 0; u < 8; u += 2) {
      acc0 = fmaf(xb[u],     wcol[k0 + u],     acc0);
      acc1 = fmaf(xb[u + 1], wcol[k0 + u + 1], acc1);
    }
  }
  Ht[hd * 1024 + node] = acc0 + acc1;
}

// ------------------------------------------------------------ layer attn ----
// 8 lanes per (dst,head).  grid 4096 = (grp<<7)|hd, 256 threads,
// 8 blocks/CU.  Block stages the 512 srcs of its (S,hd) into LDS as
// (e1,e2,e1h,e2h); each 8-lane group owns one dst and strides the table
// lane-interleaved (conflict-free, broadcast across groups); shfl_xor
// reduce; lane 0 finishes softmax + ELU and writes planar output.
template <int CROSS>
__global__ __launch_bounds__(256, 8) void attn_kernel(
    const float* __restrict__ Ht, float* __restrict__ xt_out,
    const float* __restrict__ vecs) {
  __shared__ __align__(16) float4 sE[512];  // (e1, e2, e1*h, e2*h)
  const int tid = threadIdx.x;
  const int hd  = blockIdx.x & 127;
  const int grp = blockIdx.x >> 7;          // 0..31
  const int dj  = grp * 32 + (tid >> 3);    // global dst node 0..1023
  const int Sd  = dj >> 9;                  // dst's set (uniform per block)
  const int S   = CROSS ? (1 - Sd) : Sd;    // source set
  const float a_src = vecs[hd], a_dst = vecs[128 + hd], bias = vecs[256 + hd];
  const float* __restrict__ HtH = Ht + hd * 1024;

  // stage 512 srcs, 2 per thread (coalesced reads)
#pragma unroll
  for (int u = 0; u < 2; ++u) {
    const int i = u * 256 + tid;
    const float h = HtH[S * 512 + i];
    const float s = h * a_src;
    const float e1 = __expf(s), e2 = __expf(0.2f * s);
    sE[i] = make_float4(e1, e2, e1 * h, e2 * h);
  }
  // dst-side precompute (redundant across the 8 lanes of a group)
  const float hD    = HtH[dj];
  const float d_own = hD * a_dst;
  const float F1  = __expf(d_own), F2 = __expf(0.2f * d_own);
  const float eTh = __expf(-d_own);  // exp(theta), theta = -d_own
  __syncthreads();

  const int l = tid & 7;
  float M1 = 0.f, M1h = 0.f, N2 = 0.f, N2h = 0.f;
#pragma unroll 4
  for (int ii = 0; ii < 64; ++ii) {
    const float4 r = sE[ii * 8 + l];
    const float m = (r.x >= eTh) ? 1.0f : 0.0f;
    const float n = (r.x >= eTh) ? 0.0f : 1.0f;
    M1  = fmaf(m, r.x, M1);
    M1h = fmaf(m, r.z, M1h);
    N2  = fmaf(n, r.y, N2);
    N2h = fmaf(n, r.w, N2h);
  }
  // reduce the 4 partial sums across the 8 lanes of the group
#pragma unroll
  for (int off = 1; off < 8; off <<= 1) {
    M1  += __shfl_xor(M1,  off);
    M1h += __shfl_xor(M1h, off);
    N2  += __shfl_xor(N2,  off);
    N2h += __shfl_xor(N2h, off);
  }
  if (l == 0) {
    float den = fmaf(F1, M1,  F2 * N2);
    float num = fmaf(F1, M1h, F2 * N2h);
    if (CROSS) {  // self-loop: dst node's own source score
      const float t = hD * a_src + d_own;
      const float p = __expf(fmaxf(t, 0.2f * t));
      den += p;
      num = fmaf(p, hD, num);
    }
    float o = num / (den + 1e-16f) + bias;
    o = (o > 0.f) ? o : expm1f(o);  // ELU
    xt_out[hd * 1024 + dj] = o;     // planar, coalesced across the block
  }
}

// ----------------------------------------------------- final layer: mm2 ----
// grid 512 x 256: 2 rows x 128 cols per block.  Planar x reads (broadcast
// per row).  Even-k -> acc0, odd-k -> acc1.  h2 row-major as before.
__global__ __launch_bounds__(256, 2) void mm2_kernel(
    const float* __restrict__ xt_in, const float* __restrict__ W2f,
    const float* __restrict__ vecs, float* __restrict__ h2,
    float* __restrict__ s2, float* __restrict__ d2) {
  __shared__ float rs[256], rd[256];
  const int tid = threadIdx.x;
  const int row = blockIdx.x * 2 + (tid >> 7);
  const int c = tid & 127;
  float acc0 = 0.f, acc1 = 0.f;
  for (int k0 = 0; k0 < 128; k0 += 8) {
    float xb[8];
#pragma unroll
    for (int u = 0; u < 8; ++u) xb[u] = xt_in[(k0 + u) * 1024 + row];
#pragma unroll
    for (int u = 0; u < 8; u += 2) {
      acc0 = fmaf(xb[u],     W2f[(k0 + u) * 128 + c],     acc0);
      acc1 = fmaf(xb[u + 1], W2f[(k0 + u + 1) * 128 + c], acc1);
    }
  }
  float acc = acc0 + acc1;
  h2[row * 128 + c] = acc;
  rs[tid] = acc * vecs[384 + c];  // a_src2
  rd[tid] = acc * vecs[512 + c];  // a_dst2
  __syncthreads();
  for (int off = 64; off > 0; off >>= 1) {
    if ((tid & 127) < off) { rs[tid] += rs[tid + off]; rd[tid] += rd[tid + off]; }
    __syncthreads();
  }
  if ((tid & 127) == 0) {
    s2[row] = rs[tid];
    d2[row] = rd[tid];
  }
}

// ---------------------------------------------------- final layer: attn ----
// Final conv: heads=1, ch=128, cross edges + self, no ELU, +b2.
// 512 blocks x 256 threads: 2 dsts/block.
__global__ __launch_bounds__(256, 2) void att2_kernel(
    const float* __restrict__ h2, const float* __restrict__ s2,
    const float* __restrict__ d2, const float* __restrict__ vecs,
    void* __restrict__ out, const int* __restrict__ flag) {
  __shared__ __align__(16) float pT[512 * 2];  // pT[j*2 + ld]
  const int tid = threadIdx.x;
  const int dstBase = blockIdx.x * 2;
  const int srcBase = (dstBase < 512) ? 512 : 0;  // cross edges

  for (int e = tid; e < 1024; e += 256) {
    int j = e >> 1, ld = e & 1;
    float t = s2[srcBase + j] + d2[dstBase + ld];
    pT[e] = __expf(fmaxf(t, 0.2f * t));
  }
  __syncthreads();

  const int c = tid & 127;
  const int g = tid >> 7;            // 0 or 1 -> dst within block
  const int i0 = dstBase + g;
  float den = 0.f, num = 0.f;
  const float* hrow = h2 + srcBase * 128 + c;
  for (int j0 = 0; j0 < 512; j0 += 8) {
    float hb[8];
#pragma unroll
    for (int u = 0; u < 8; ++u) hb[u] = hrow[(j0 + u) * 128];
#pragma unroll
    for (int u = 0; u < 8; ++u) {
      float p = pT[(j0 + u) * 2 + g];
      den += p;
      num = fmaf(p, hb[u], num);
    }
  }
  // self-loop
  float ts = s2[i0] + d2[i0];
  float ps = __expf(fmaxf(ts, 0.2f * ts));
  den += ps;
  num = fmaf(ps, h2[i0 * 128 + c], num);

  float o = num / (den + 1e-16f) + vecs[640 + c];
  if (*flag) ((bf16*)out)[i0 * 128 + c] = __float2bfloat16(o);
  else       ((float*)out)[i0 * 128 + c] = o;
}

// ------------------------------------------------------------- launcher ----
extern "C" void kernel_launch(void* const* d_in, const int* in_sizes, int n_in,
                              void* d_out, int out_size, void* d_ws, size_t ws_size,
                              hipStream_t stream) {
  (void)in_sizes; (void)n_in; (void)out_size; (void)ws_size;
  float* ws   = (float*)d_ws;
  float* xtA  = ws;            // 131072 (planar [ch][node])
  float* xtB  = ws + 131072;   // 131072 (planar [ch][node])
  float* h2   = ws + 262144;   // 131072 (row-major); ALSO aliased as Ht
  float* Ht   = h2;            // Ht[hd*1024+node]; dead once mm2 runs
  float* W1t  = ws + 393216;   // 16384 (transposed W1)
  float* W2f  = ws + 409600;   // 16384
  float* vecs = ws + 425984;   // 768
  float* s2   = ws + 426752;   // 1024
  float* d2   = ws + 427776;   // 1024
  int*   flag = (int*)(ws + 428800);

  prep_kernel<<<256, 256, 0, stream>>>(d_in[0], d_in[1], d_in[2], d_in[3],
                                       d_in[4], d_in[5], d_in[6], d_in[7],
                                       d_in[8], d_in[9], xtA, W1t, W2f, vecs,
                                       flag);
  // L1 inside
  gemm_kernel<<<512, 256, 0, stream>>>(xtA, W1t, Ht);
  attn_kernel<0><<<4096, 256, 0, stream>>>(Ht, xtB, vecs);
  // L2 cross
  gemm_kernel<<<512, 256, 0, stream>>>(xtB, W1t, Ht);
  attn_kernel<1><<<4096, 256, 0, stream>>>(Ht, xtA, vecs);
  // L3 inside
  gemm_kernel<<<512, 256, 0, stream>>>(xtA, W1t, Ht);
  attn_kernel<0><<<4096, 256, 0, stream>>>(Ht, xtB, vecs);
  // L4 cross
  gemm_kernel<<<512, 256, 0, stream>>>(xtB, W1t, Ht);
  attn_kernel<1><<<4096, 256, 0, stream>>>(Ht, xtA, vecs);
  // final layer
  mm2_kernel<<<512, 256, 0, stream>>>(xtA, W2f, vecs, h2, s2, d2);
  att2_kernel<<<512, 256, 0, stream>>>(h2, s2, d2, vecs, d_out, flag);
}